// Round 1
// baseline (648.605 us; speedup 1.0000x reference)
//
#include <hip/hip_runtime.h>
#include <stdint.h>

#define N_TOK 8192
#define C_DIM 1024
#define H_DIM 3072
#define N_EXP 8
#define N_ASSIGN (N_TOK * 2)

typedef __attribute__((ext_vector_type(8))) short short8;
typedef __attribute__((ext_vector_type(4))) float f32x4;

__device__ __forceinline__ unsigned short f2bf(float f) {
    union { float f; uint32_t u; } v; v.f = f;
    uint32_t r = (v.u + 0x7FFFu + ((v.u >> 16) & 1u)) >> 16;
    return (unsigned short)r;
}

#define GLDS16(SRC, DST) __builtin_amdgcn_global_load_lds( \
    (const __attribute__((address_space(1))) void*)(SRC),  \
    (__attribute__((address_space(3))) void*)(DST), 16, 0, 0)

// ---------------- transpose + fp32->bf16 convert: out[col][row] = in[row][col], per expert (grid.z)
__global__ void transpose_bf16_kernel(const float* __restrict__ in, unsigned short* __restrict__ out,
                                      int rows, int cols) {
    __shared__ float tile[32][33];
    int e = blockIdx.z;
    const float* ip = in + (size_t)e * rows * cols;
    unsigned short* op = out + (size_t)e * rows * cols;
    int col0 = blockIdx.x * 32;
    int row0 = blockIdx.y * 32;
    int tx = threadIdx.x, ty = threadIdx.y;
    tile[ty][tx] = ip[(size_t)(row0 + ty) * cols + col0 + tx];
    __syncthreads();
    op[(size_t)(col0 + ty) * rows + row0 + tx] = f2bf(tile[tx][ty]);
}

// ---------------- router: logits = x @ Wr, softmax, top-2 (lowest-index ties), renorm; pi/cnt stats
__global__ __launch_bounds__(256) void router_kernel(const float* __restrict__ x, const float* __restrict__ Wr,
                                                     int2* __restrict__ idx2, float2* __restrict__ wgt2,
                                                     float* __restrict__ piAcc, int* __restrict__ cntAcc) {
    __shared__ float s_pi[8];
    __shared__ int s_cnt[8];
    int t = threadIdx.x;
    if (t < 8) { s_pi[t] = 0.f; s_cnt[t] = 0; }
    __syncthreads();
    int lane = t & 63;
    int wid = t >> 6;
    int gwv = blockIdx.x * 4 + wid;
    int nw = gridDim.x * 4;
    for (int n = gwv; n < N_TOK; n += nw) {
        float acc[8];
#pragma unroll
        for (int e = 0; e < 8; e++) acc[e] = 0.f;
        const float* xr = x + (size_t)n * C_DIM;
#pragma unroll
        for (int j = 0; j < 16; j++) {
            int k = lane + 64 * j;
            float xv = xr[k];
            const float4* wr4 = (const float4*)(Wr + (size_t)k * 8);
            float4 a = wr4[0], b = wr4[1];
            acc[0] += xv * a.x; acc[1] += xv * a.y; acc[2] += xv * a.z; acc[3] += xv * a.w;
            acc[4] += xv * b.x; acc[5] += xv * b.y; acc[6] += xv * b.z; acc[7] += xv * b.w;
        }
#pragma unroll
        for (int off = 1; off < 64; off <<= 1) {
#pragma unroll
            for (int e = 0; e < 8; e++) acc[e] += __shfl_xor(acc[e], off, 64);
        }
        // softmax probs (fp32)
        float m = acc[0];
#pragma unroll
        for (int e = 1; e < 8; e++) m = fmaxf(m, acc[e]);
        float p[8]; float s = 0.f;
#pragma unroll
        for (int e = 0; e < 8; e++) { p[e] = __expf(acc[e] - m); s += p[e]; }
        float inv = 1.f / s;
#pragma unroll
        for (int e = 0; e < 8; e++) p[e] *= inv;
        // top-2 by logits (monotone with probs; lowest index wins ties, matching lax.top_k)
        int i0 = 0; float l0 = acc[0];
#pragma unroll
        for (int e = 1; e < 8; e++) if (acc[e] > l0) { l0 = acc[e]; i0 = e; }
        int i1 = -1; float l1 = -1e30f;
#pragma unroll
        for (int e = 0; e < 8; e++) if (e != i0 && acc[e] > l1) { l1 = acc[e]; i1 = e; }
        if (lane == 0) {
            float v0 = p[i0], v1 = p[i1];
            float rs = 1.f / (v0 + v1);
            idx2[n] = make_int2(i0, i1);
            wgt2[n] = make_float2(v0 * rs, v1 * rs);
            atomicAdd(&s_cnt[i0], 1);
            atomicAdd(&s_cnt[i1], 1);
#pragma unroll
            for (int e = 0; e < 8; e++) atomicAdd(&s_pi[e], p[e]);
        }
    }
    __syncthreads();
    if (t < 8) { atomicAdd(&piAcc[t], s_pi[t]); atomicAdd(&cntAcc[t], s_cnt[t]); }
}

// ---------------- offsets (exclusive scan of cnt) + aux loss
__global__ void finalize_router_kernel(const int* __restrict__ cnt, const float* __restrict__ pi,
                                       int* __restrict__ off, float* __restrict__ aux_out) {
    if (threadIdx.x == 0) {
        int o = 0;
        float dot = 0.f;
        for (int e = 0; e < 8; e++) {
            off[e] = o;
            o += cnt[e];
            dot += (float)cnt[e] * pi[e];
        }
        aux_out[0] = 0.01f * 8.f * dot / ((float)N_TOK * (float)N_TOK);
    }
}

// ---------------- scatter: build per-expert token/weight lists (block-aggregated cursors)
__global__ __launch_bounds__(256) void scatter_kernel(const int2* __restrict__ idx2, const float2* __restrict__ wgt2,
                                                      const int* __restrict__ off, int* __restrict__ cursor,
                                                      int* __restrict__ tok, float* __restrict__ gwArr) {
    __shared__ int lcnt[8], lbase[8];
    int t = threadIdx.x;
    if (t < 8) lcnt[t] = 0;
    __syncthreads();
    int a = blockIdx.x * 256 + t;
    int n = a >> 1, k = a & 1;
    int2 id = idx2[n];
    float2 w = wgt2[n];
    int e = k ? id.y : id.x;
    float wv = k ? w.y : w.x;
    int rank = atomicAdd(&lcnt[e], 1);
    __syncthreads();
    if (t < 8) lbase[t] = atomicAdd(&cursor[t], lcnt[t]);
    __syncthreads();
    int pos = off[e] + lbase[e] + rank;
    tok[pos] = n;
    gwArr[pos] = wv;
}

// ---------------- gather x rows -> packed bf16 xg (one wave per assignment row)
__global__ __launch_bounds__(256) void gather_kernel(const float* __restrict__ x, const int* __restrict__ tok,
                                                     unsigned short* __restrict__ xg) {
    int wid = threadIdx.x >> 6, lane = threadIdx.x & 63;
    int row = blockIdx.x * 4 + wid;
    int n = tok[row];
    const float4* src = (const float4*)(x + (size_t)n * C_DIM);
    ushort4* dst = (ushort4*)(xg + (size_t)row * C_DIM);
#pragma unroll
    for (int j = 0; j < 4; j++) {
        float4 v = src[lane + 64 * j];
        ushort4 o;
        o.x = f2bf(v.x); o.y = f2bf(v.y); o.z = f2bf(v.z); o.w = f2bf(v.w);
        dst[lane + 64 * j] = o;
    }
}

// ---------------- grouped GEMM, 128x128 tile, BK=64, 4 waves (2x2), 16x16x32 bf16 MFMA
// B is stored transposed: Bt[row = output col][k]. XOR swizzle (row&7)<<4 on LDS bytes,
// applied as inverse-swizzled global SOURCE + swizzled READ (global_load_lds writes linearly).
// EPI=0: h[assignRow][n0+c] = bf16(silu(acc));  EPI=1: atomicAdd(out[tok*C + n0+c], gw*acc)
template <int EPI>
__global__ __launch_bounds__(256) void moe_gemm_kernel(
    const unsigned short* __restrict__ A, int ldA,
    const unsigned short* __restrict__ Bt, int ldB, int bRowOff, int bColOff,
    int K,
    const int* __restrict__ cnt, const int* __restrict__ off,
    const int* __restrict__ tok, const float* __restrict__ gwArr,
    unsigned short* __restrict__ hs, int ldH,
    float* __restrict__ out) {
    __shared__ unsigned short As[128 * 64];
    __shared__ unsigned short Bs[128 * 64];
    int e = blockIdx.z;
    int M = cnt[e];
    int m0 = blockIdx.x * 128;
    if (m0 >= M) return;
    int baseRow = off[e];
    int n0 = blockIdx.y * 128;
    int t = threadIdx.x;
    int lane = t & 63;
    int wid = t >> 6;
    int wm = (wid >> 1) * 64, wn = (wid & 1) * 64;

    f32x4 acc[4][4];
#pragma unroll
    for (int i = 0; i < 4; i++)
#pragma unroll
        for (int j = 0; j < 4; j++) acc[i][j] = (f32x4)0.f;

    const size_t eB = (size_t)e * (size_t)(C_DIM * H_DIM);
    const unsigned short* Bex = Bt + eB;

    for (int k0 = 0; k0 < K; k0 += 64) {
        // stage A tile [128 rows][64 k]
#pragma unroll
        for (int i = 0; i < 4; i++) {
            int o16 = i * 256 + t;            // 16B chunk id
            int row = o16 >> 3;               // 8 chunks per row
            int bb = (o16 & 7) << 4;          // byte within row
            int sb = bb ^ ((row & 7) << 4);   // inverse-swizzled source bytes
            int colE = k0 + (sb >> 1);
            int rg = m0 + row; if (rg > M - 1) rg = M - 1;
            const unsigned short* src = A + (size_t)(baseRow + rg) * ldA + colE;
            unsigned short* dst = &As[(size_t)(i * 256 + (t & ~63)) * 8];
            GLDS16(src, dst);
        }
        // stage B tile [128 out-cols][64 k]
#pragma unroll
        for (int i = 0; i < 4; i++) {
            int o16 = i * 256 + t;
            int row = o16 >> 3;
            int bb = (o16 & 7) << 4;
            int sb = bb ^ ((row & 7) << 4);
            int colE = bColOff + k0 + (sb >> 1);
            int rowB = bRowOff + n0 + row;
            const unsigned short* src = Bex + (size_t)rowB * ldB + colE;
            unsigned short* dst = &Bs[(size_t)(i * 256 + (t & ~63)) * 8];
            GLDS16(src, dst);
        }
        __syncthreads();
#pragma unroll
        for (int kk = 0; kk < 2; kk++) {
            short8 a[4], b[4];
#pragma unroll
            for (int m = 0; m < 4; m++) {
                int row = wm + m * 16 + (lane & 15);
                int cb = (kk * 64 + ((lane >> 4) << 4)) ^ ((row & 7) << 4);
                a[m] = *(const short8*)&As[row * 64 + (cb >> 1)];
            }
#pragma unroll
            for (int n = 0; n < 4; n++) {
                int row = wn + n * 16 + (lane & 15);
                int cb = (kk * 64 + ((lane >> 4) << 4)) ^ ((row & 7) << 4);
                b[n] = *(const short8*)&Bs[row * 64 + (cb >> 1)];
            }
#pragma unroll
            for (int m = 0; m < 4; m++)
#pragma unroll
                for (int n = 0; n < 4; n++)
                    acc[m][n] = __builtin_amdgcn_mfma_f32_16x16x32_bf16(a[m], b[n], acc[m][n], 0, 0, 0);
        }
        __syncthreads();
    }

    int gRow = (lane >> 4) * 4;
    int cLane = lane & 15;
#pragma unroll
    for (int m = 0; m < 4; m++) {
#pragma unroll
        for (int j = 0; j < 4; j++) {
            int r = m0 + wm + m * 16 + gRow + j;
            if (r < M) {
                if (EPI == 0) {
#pragma unroll
                    for (int n = 0; n < 4; n++) {
                        int c = n0 + wn + n * 16 + cLane;
                        float v = acc[m][n][j];
                        float sv = v / (1.f + __expf(-v));
                        hs[(size_t)(baseRow + r) * ldH + c] = f2bf(sv);
                    }
                } else {
                    int token = tok[baseRow + r];
                    float w = gwArr[baseRow + r];
#pragma unroll
                    for (int n = 0; n < 4; n++) {
                        int c = n0 + wn + n * 16 + cLane;
                        atomicAdd(&out[(size_t)token * C_DIM + c], w * acc[m][n][j]);
                    }
                }
            }
        }
    }
}

extern "C" void kernel_launch(void* const* d_in, const int* in_sizes, int n_in,
                              void* d_out, int out_size, void* d_ws, size_t ws_size,
                              hipStream_t stream) {
    const float* x = (const float*)d_in[0];
    const float* W1 = (const float*)d_in[1];
    const float* W2 = (const float*)d_in[2];
    const float* Wr = (const float*)d_in[3];
    float* out = (float*)d_out;

    // workspace layout (256B aligned chunks)
    char* p = (char*)d_ws;
    auto alloc = [&](size_t bytes) {
        char* r = p;
        p += (bytes + 255) & ~(size_t)255;
        return r;
    };
    float* pi = (float*)alloc(8 * sizeof(float));
    int* cntA = (int*)alloc(8 * sizeof(int));
    int* cursor = (int*)alloc(8 * sizeof(int));
    int* offA = (int*)alloc(8 * sizeof(int));
    int2* idx2 = (int2*)alloc((size_t)N_TOK * sizeof(int2));
    float2* wgt2 = (float2*)alloc((size_t)N_TOK * sizeof(float2));
    int* tok = (int*)alloc((size_t)N_ASSIGN * sizeof(int));
    float* gwA = (float*)alloc((size_t)N_ASSIGN * sizeof(float));
    unsigned short* W1bT = (unsigned short*)alloc((size_t)N_EXP * C_DIM * H_DIM * 2);
    unsigned short* W2bT = (unsigned short*)alloc((size_t)N_EXP * C_DIM * H_DIM * 2);
    unsigned short* xg = (unsigned short*)alloc((size_t)N_ASSIGN * C_DIM * 2);
    size_t used = (size_t)(p - (char*)d_ws);
    size_t remain = ws_size > used ? ws_size - used : 0;
    int HC = H_DIM;
    while (HC > 384 && (size_t)N_ASSIGN * HC * 2 > remain) HC >>= 1;
    unsigned short* hs = (unsigned short*)p;

    hipMemsetAsync(d_ws, 0, 1024, stream);                                      // pi, cnt, cursor, off
    hipMemsetAsync(d_out, 0, (size_t)N_TOK * C_DIM * sizeof(float), stream);    // accumulated output

    dim3 tb(32, 32, 1);
    transpose_bf16_kernel<<<dim3(H_DIM / 32, C_DIM / 32, N_EXP), tb, 0, stream>>>(W1, W1bT, C_DIM, H_DIM);
    transpose_bf16_kernel<<<dim3(C_DIM / 32, H_DIM / 32, N_EXP), tb, 0, stream>>>(W2, W2bT, H_DIM, C_DIM);

    router_kernel<<<256, 256, 0, stream>>>(x, Wr, idx2, wgt2, pi, cntA);
    finalize_router_kernel<<<1, 64, 0, stream>>>(cntA, pi, offA, out + (size_t)N_TOK * C_DIM);
    scatter_kernel<<<N_ASSIGN / 256, 256, 0, stream>>>(idx2, wgt2, offA, cursor, tok, gwA);
    gather_kernel<<<N_ASSIGN / 4, 256, 0, stream>>>(x, tok, xg);

    int nChunks = H_DIM / HC;
    for (int ci = 0; ci < nChunks; ++ci) {
        int h0 = ci * HC;
        moe_gemm_kernel<0><<<dim3(64, HC / 128, N_EXP), 256, 0, stream>>>(
            xg, C_DIM, W1bT, C_DIM, h0, 0, C_DIM, cntA, offA, tok, gwA, hs, HC, out);
        moe_gemm_kernel<1><<<dim3(64, C_DIM / 128, N_EXP), 256, 0, stream>>>(
            hs, HC, W2bT, H_DIM, 0, h0, HC, cntA, offA, tok, gwA, hs, HC, out);
    }
}